// Round 13
// baseline (139.563 us; speedup 1.0000x reference)
//
#include <hip/hip_runtime.h>
#include <math.h>

constexpr int Bn = 1024, DH = 2048, K1 = 4096, DO = 1024, NL = 128;
constexpr int MN = Bn * DO;  // 1M elements

typedef __bf16 bf16x8 __attribute__((ext_vector_type(8)));
typedef short  s16x8  __attribute__((ext_vector_type(8)));
typedef float  f32x4  __attribute__((ext_vector_type(4)));

__device__ __forceinline__ unsigned short f2bf(float f) {
  union { float f; unsigned u; } v; v.f = f;
  unsigned r = v.u + 0x7FFFu + ((v.u >> 16) & 1u);  // RNE
  return (unsigned short)(r >> 16);
}
__device__ __forceinline__ float bf2f(unsigned h) {
  union { unsigned u; float f; } v; v.u = h << 16; return v.f;
}

// ---------- prep: concat+relu+bf16 (blocks 0..2047) + W1/W2 transposes ----------
__global__ __launch_bounds__(256)
void prep(const float* __restrict__ sbj, const float* __restrict__ obj,
          const float* __restrict__ W1, const float* __restrict__ W2,
          unsigned short* __restrict__ Abf,
          unsigned short* __restrict__ W1t, unsigned short* __restrict__ W2t) {
  const int tid = threadIdx.x;
  if (blockIdx.x < 2048) {
    const int t = blockIdx.x * 256 + tid;
    const int m = t >> 9;
    const int k = (t & 511) << 3;
    const float* src = (k < DH) ? sbj + (size_t)m * DH + k
                                : obj + (size_t)m * DH + (k - DH);
    const float4 a = ((const float4*)src)[0];
    const float4 b = ((const float4*)src)[1];
    uint4 o;
    o.x = (unsigned)f2bf(fmaxf(a.x, 0.f)) | ((unsigned)f2bf(fmaxf(a.y, 0.f)) << 16);
    o.y = (unsigned)f2bf(fmaxf(a.z, 0.f)) | ((unsigned)f2bf(fmaxf(a.w, 0.f)) << 16);
    o.z = (unsigned)f2bf(fmaxf(b.x, 0.f)) | ((unsigned)f2bf(fmaxf(b.y, 0.f)) << 16);
    o.w = (unsigned)f2bf(fmaxf(b.z, 0.f)) | ((unsigned)f2bf(fmaxf(b.w, 0.f)) << 16);
    *(uint4*)&Abf[(size_t)m * K1 + k] = o;
    return;
  }
  __shared__ float tl[64][65];
  const int tb = blockIdx.x - 2048;
  int by = tb >> 4;
  const int c0 = (tb & 15) * 64;
  const float* in; unsigned short* out; int R;
  if (by < 64) { in = W1; out = W1t; R = K1; }
  else         { in = W2; out = W2t; R = DO; by -= 64; }
  const int r0 = by * 64;
  {
    const int rr = tid >> 4, cc = (tid & 15) * 4;
    #pragma unroll
    for (int i = 0; i < 4; ++i) {
      const float4 v = *(const float4*)&in[(size_t)(r0 + rr + i * 16) * DO + c0 + cc];
      tl[rr + i * 16][cc + 0] = v.x; tl[rr + i * 16][cc + 1] = v.y;
      tl[rr + i * 16][cc + 2] = v.z; tl[rr + i * 16][cc + 3] = v.w;
    }
  }
  __syncthreads();
  {
    const int r4 = (tid & 15) * 4;
    #pragma unroll
    for (int i = 0; i < 4; ++i) {
      const int cr = i * 16 + (tid >> 4);
      uint2 o;
      o.x = (unsigned)f2bf(tl[r4 + 0][cr]) | ((unsigned)f2bf(tl[r4 + 1][cr]) << 16);
      o.y = (unsigned)f2bf(tl[r4 + 2][cr]) | ((unsigned)f2bf(tl[r4 + 3][cr]) << 16);
      *(uint2*)&out[(size_t)(c0 + cr) * R + r0 + r4] = o;
    }
  }
}

// ---------- GEMM1: 128x128 tile, 4 waves in 2x2 (64x64 quadrant each),
// BK=64, split-K=8 with z = XCD (bid&7). Writes bf16 partials P[z][1024][1024]. ----------
template <int KSLICE>
__global__ __launch_bounds__(256, 2)
void mfma_gemm(const unsigned short* __restrict__ A,
               const unsigned short* __restrict__ Bt,
               unsigned short* __restrict__ P, int K) {
  __shared__ __align__(16) unsigned short smem[2 * 128 * 64];  // 32 KB
  unsigned short* LA = smem;
  unsigned short* LB = smem + 128 * 64;

  const int tid = threadIdx.x;
  const int w = tid >> 6, l = tid & 63;
  const int bid = blockIdx.x;
  const int z = bid & 7, t = bid >> 3;
  const int m0 = (t >> 3) * 128, n0 = (t & 7) * 128;
  const int kb = z * KSLICE;

  f32x4 acc[4][4] = {};

  constexpr int NIT = KSLICE / 64;
  for (int it = 0; it < NIT; ++it) {
    const int k0 = kb + it * 64;
    #pragma unroll
    for (int i = 0; i < 4; ++i) {
      const int c = i * 256 + tid, row = c >> 3, kc = c & 7;
      const int kcg = kc ^ (row & 7);
      __builtin_amdgcn_global_load_lds(
          (const __attribute__((address_space(1))) unsigned int*)(A + (size_t)(m0 + row) * K + k0 + kcg * 8),
          (__attribute__((address_space(3))) unsigned int*)&LA[c * 8], 16, 0, 0);
    }
    #pragma unroll
    for (int i = 0; i < 4; ++i) {
      const int c = i * 256 + tid, row = c >> 3, kc = c & 7;
      const int kcg = kc ^ (row & 7);
      __builtin_amdgcn_global_load_lds(
          (const __attribute__((address_space(1))) unsigned int*)(Bt + (size_t)(n0 + row) * K + k0 + kcg * 8),
          (__attribute__((address_space(3))) unsigned int*)&LB[c * 8], 16, 0, 0);
    }
    __syncthreads();

    #pragma unroll
    for (int s = 0; s < 2; ++s) {
      const int kcq = s * 4 + (l >> 4);
      bf16x8 af[4], bfr[4];
      #pragma unroll
      for (int i = 0; i < 4; ++i) {
        const int r = (w >> 1) * 64 + i * 16 + (l & 15);
        const int kca = kcq ^ (r & 7);
        af[i] = __builtin_bit_cast(bf16x8, *(const s16x8*)&LA[(r * 8 + kca) * 8]);
      }
      #pragma unroll
      for (int j = 0; j < 4; ++j) {
        const int rr = (w & 1) * 64 + j * 16 + (l & 15);
        const int kcb = kcq ^ (rr & 7);
        bfr[j] = __builtin_bit_cast(bf16x8, *(const s16x8*)&LB[(rr * 8 + kcb) * 8]);
      }
      #pragma unroll
      for (int i = 0; i < 4; ++i)
        #pragma unroll
        for (int j = 0; j < 4; ++j)
          acc[i][j] = __builtin_amdgcn_mfma_f32_16x16x32_bf16(af[i], bfr[j], acc[i][j], 0, 0, 0);
    }
    __syncthreads();
  }

  unsigned short* Pz = P + (size_t)z * MN;
  #pragma unroll
  for (int i = 0; i < 4; ++i) {
    #pragma unroll
    for (int r = 0; r < 4; ++r) {
      const int m = m0 + (w >> 1) * 64 + i * 16 + (l >> 4) * 4 + r;
      #pragma unroll
      for (int j = 0; j < 4; ++j) {
        const int n = n0 + (w & 1) * 64 + j * 16 + (l & 15);
        Pz[(size_t)m * DO + n] = f2bf(acc[i][j][r]);
      }
    }
  }
}

// ---------- combine1: H = relu(sum_z bf16 P[z] + b1) -> bf16 ----------
__global__ __launch_bounds__(256)
void combine1(const unsigned short* __restrict__ P, const float* __restrict__ bias,
              unsigned short* __restrict__ out) {
  const int row = blockIdx.x, t = threadIdx.x;
  const size_t base = (size_t)row * DO + t * 4;
  float s0 = 0.f, s1 = 0.f, s2 = 0.f, s3 = 0.f;
  #pragma unroll
  for (int c = 0; c < 8; ++c) {
    const uint2 wv = *(const uint2*)&P[(size_t)c * MN + base];
    s0 += bf2f(wv.x & 0xFFFFu); s1 += bf2f(wv.x >> 16);
    s2 += bf2f(wv.y & 0xFFFFu); s3 += bf2f(wv.y >> 16);
  }
  const f32x4 bb = *(const f32x4*)&bias[t * 4];
  s0 = fmaxf(s0 + bb[0], 0.f); s1 = fmaxf(s1 + bb[1], 0.f);
  s2 = fmaxf(s2 + bb[2], 0.f); s3 = fmaxf(s3 + bb[3], 0.f);
  uint2 o;
  o.x = (unsigned)f2bf(s0) | ((unsigned)f2bf(s1) << 16);
  o.y = (unsigned)f2bf(s2) | ((unsigned)f2bf(s3) << 16);
  *(uint2*)&out[base] = o;
}

// ---------- GEMM2 + score fusion: 64x64 E-tile (m=batch, n=d-chunk) computed
// in registers (in-block 4-wave k-split, LDS tree-reduce), then the SAME block
// computes score partials for its (64-batch x 128-label x 64-d) unit:
// E-tile -> LDS es[d][b] fp32, labels -> LDS ls[d][l] bf16, r5-proven inner
// loop over two 32-batch halves. E never touches HBM. ----------
__global__ __launch_bounds__(256, 4)
void gemm2_score(const unsigned short* __restrict__ A,
                 const unsigned short* __restrict__ Bt,
                 const float* __restrict__ b2,
                 const float* __restrict__ labs,
                 float* __restrict__ SP) {
  __shared__ __align__(16) char smem[34048];  // max(LA+LB 32K, es 16640 + ls 17408)
  unsigned short* LA = (unsigned short*)smem;
  unsigned short* LB = (unsigned short*)smem + 64 * 128;

  const int tid = threadIdx.x;
  const int w = tid >> 6, l = tid & 63;
  const int bid = blockIdx.x;
  const int m0 = (bid >> 4) * 64;   // batch-tile base
  const int d0 = (bid & 15) * 64;   // d-chunk base (= n-tile base)

  f32x4 acc[4][4] = {};

  for (int it = 0; it < 8; ++it) {  // K=1024, BK=128
    const int k0 = it * 128;
    #pragma unroll
    for (int i = 0; i < 4; ++i) {
      const int c = i * 256 + tid, m = c >> 4, kc = c & 15;
      const int kcg = (kc & 8) | ((kc & 7) ^ (m & 7));
      __builtin_amdgcn_global_load_lds(
          (const __attribute__((address_space(1))) unsigned int*)(A + (size_t)(m0 + m) * DO + k0 + kcg * 8),
          (__attribute__((address_space(3))) unsigned int*)&LA[c * 8], 16, 0, 0);
    }
    #pragma unroll
    for (int i = 0; i < 4; ++i) {
      const int c = i * 256 + tid, n = c >> 4, kc = c & 15;
      const int kcg = (kc & 8) | ((kc & 7) ^ (n & 7));
      __builtin_amdgcn_global_load_lds(
          (const __attribute__((address_space(1))) unsigned int*)(Bt + (size_t)(d0 + n) * DO + k0 + kcg * 8),
          (__attribute__((address_space(3))) unsigned int*)&LB[c * 8], 16, 0, 0);
    }
    __syncthreads();

    const int kcq = w * 4 + (l >> 4);
    bf16x8 af[4], bfr[4];
    #pragma unroll
    for (int i = 0; i < 4; ++i) {
      const int r = i * 16 + (l & 15);
      const int kca = (kcq & 8) | ((kcq & 7) ^ (r & 7));
      af[i]  = __builtin_bit_cast(bf16x8, *(const s16x8*)&LA[(r * 16 + kca) * 8]);
      bfr[i] = __builtin_bit_cast(bf16x8, *(const s16x8*)&LB[(r * 16 + kca) * 8]);
    }
    #pragma unroll
    for (int i = 0; i < 4; ++i)
      #pragma unroll
      for (int j = 0; j < 4; ++j)
        acc[i][j] = __builtin_amdgcn_mfma_f32_16x16x32_bf16(af[i], bfr[j], acc[i][j], 0, 0, 0);
    __syncthreads();
  }

  // ---- 4-wave k-split tree reduction (r7-proven, no early return) ----
  float* red = (float*)smem;
  if (w >= 2) {
    #pragma unroll
    for (int i = 0; i < 4; ++i)
      #pragma unroll
      for (int j = 0; j < 4; ++j)
        *(f32x4*)&red[(w - 2) * 4096 + ((i * 4 + j) * 64 + l) * 4] = acc[i][j];
  }
  __syncthreads();
  if (w < 2) {
    #pragma unroll
    for (int i = 0; i < 4; ++i)
      #pragma unroll
      for (int j = 0; j < 4; ++j)
        acc[i][j] += *(const f32x4*)&red[w * 4096 + ((i * 4 + j) * 64 + l) * 4];
  }
  __syncthreads();
  if (w == 1) {
    #pragma unroll
    for (int i = 0; i < 2; ++i)
      #pragma unroll
      for (int j = 0; j < 4; ++j)
        *(f32x4*)&red[((i * 4 + j) * 64 + l) * 4] = acc[i][j];
  } else if (w == 0) {
    #pragma unroll
    for (int i = 0; i < 2; ++i)
      #pragma unroll
      for (int j = 0; j < 4; ++j)
        *(f32x4*)&red[2048 + ((i * 4 + j) * 64 + l) * 4] = acc[i + 2][j];
  }
  __syncthreads();
  if (w == 0) {
    #pragma unroll
    for (int i = 0; i < 2; ++i)
      #pragma unroll
      for (int j = 0; j < 4; ++j)
        acc[i][j] += *(const f32x4*)&red[((i * 4 + j) * 64 + l) * 4];
  } else if (w == 1) {
    #pragma unroll
    for (int i = 0; i < 2; ++i)
      #pragma unroll
      for (int j = 0; j < 4; ++j)
        acc[i + 2][j] += *(const f32x4*)&red[2048 + ((i * 4 + j) * 64 + l) * 4];
  }
  __syncthreads();  // red fully consumed before es/ls overwrite LDS

  // ---- epilogue into LDS: es[d][b] = E-tile + b2 ; ls[d][l] = labels (bf16) ----
  float* es = (float*)smem;                              // [64][65] f32 = 16640 B
  unsigned short* ls = (unsigned short*)(smem + 16640);  // [64][136] bf16 = 17408 B
  if (w == 0) {  // rows m_local 0..31 (C/D: n=j*16+(l&15), m=i*16+(l>>4)*4+r)
    #pragma unroll
    for (int j = 0; j < 4; ++j) {
      const int n = j * 16 + (l & 15);
      const float bb = b2[d0 + n];
      #pragma unroll
      for (int i = 0; i < 2; ++i)
        #pragma unroll
        for (int r = 0; r < 4; ++r)
          es[n * 65 + i * 16 + (l >> 4) * 4 + r] = acc[i][j][r] + bb;
    }
  } else if (w == 1) {  // rows m_local 32..63
    #pragma unroll
    for (int j = 0; j < 4; ++j) {
      const int n = j * 16 + (l & 15);
      const float bb = b2[d0 + n];
      #pragma unroll
      for (int i = 0; i < 2; ++i)
        #pragma unroll
        for (int r = 0; r < 4; ++r)
          es[n * 65 + (i + 2) * 16 + (l >> 4) * 4 + r] = acc[i + 2][j][r] + bb;
    }
  }
  #pragma unroll
  for (int i = 0; i < 8; ++i) {  // labels 128 l x 64 d: 2048 float4 slots
    const int s = i * 256 + tid, lr = s >> 4, dq = s & 15;
    const float4 v = *(const float4*)&labs[(size_t)lr * DO + d0 + dq * 4];
    ls[(dq * 4 + 0) * 136 + lr] = f2bf(v.x);
    ls[(dq * 4 + 1) * 136 + lr] = f2bf(v.y);
    ls[(dq * 4 + 2) * 136 + lr] = f2bf(v.z);
    ls[(dq * 4 + 3) * 136 + lr] = f2bf(v.w);
  }
  __syncthreads();

  // ---- score partials: two 32-batch halves, r5-proven inner loop ----
  const int tb = tid & 15;   // b-pair within half
  const int tl = tid >> 4;   // label-octet
  float* SPz = SP + (size_t)(bid & 15) * (Bn * NL);
  #pragma unroll
  for (int h = 0; h < 2; ++h) {
    float a2[2][8] = {};
    for (int dd = 0; dd < 64; ++dd) {
      const float e0 = es[dd * 65 + h * 32 + tb * 2 + 0];
      const float e1 = es[dd * 65 + h * 32 + tb * 2 + 1];
      const uint4 lw = *(const uint4*)&ls[dd * 136 + tl * 8];
      const float lv[8] = {bf2f(lw.x & 0xFFFFu), bf2f(lw.x >> 16),
                           bf2f(lw.y & 0xFFFFu), bf2f(lw.y >> 16),
                           bf2f(lw.z & 0xFFFFu), bf2f(lw.z >> 16),
                           bf2f(lw.w & 0xFFFFu), bf2f(lw.w >> 16)};
      #pragma unroll
      for (int j = 0; j < 8; ++j) {
        float t0 = fmaxf(lv[j] - e0, 0.f); a2[0][j] = fmaf(t0, t0, a2[0][j]);
        float t1 = fmaxf(lv[j] - e1, 0.f); a2[1][j] = fmaf(t1, t1, a2[1][j]);
      }
    }
    #pragma unroll
    for (int i = 0; i < 2; ++i) {
      const size_t base = (size_t)(m0 + h * 32 + tb * 2 + i) * NL + tl * 8;
      float4 v0 = {a2[i][0], a2[i][1], a2[i][2], a2[i][3]};
      float4 v1 = {a2[i][4], a2[i][5], a2[i][6], a2[i][7]};
      *(float4*)&SPz[base]     = v0;
      *(float4*)&SPz[base + 4] = v1;
    }
  }
}

// ---------- final: scores = -sqrt(sum of 16 d-chunk partials) ----------
__global__ __launch_bounds__(256)
void score_reduce(const float* __restrict__ SP, float* __restrict__ out) {
  const size_t i4 = (size_t)blockIdx.x * 256 + threadIdx.x;
  f32x4 s = ((const f32x4*)SP)[i4];
  #pragma unroll
  for (int c = 1; c < 16; ++c) s += ((const f32x4*)SP)[(size_t)c * 32768 + i4];
  f32x4 o = {-sqrtf(s[0]), -sqrtf(s[1]), -sqrtf(s[2]), -sqrtf(s[3])};
  ((f32x4*)out)[i4] = o;
}

extern "C" void kernel_launch(void* const* d_in, const int* in_sizes, int n_in,
                              void* d_out, int out_size, void* d_ws, size_t ws_size,
                              hipStream_t stream) {
  const float* sbj  = (const float*)d_in[0];
  const float* obj  = (const float*)d_in[1];
  const float* W1   = (const float*)d_in[2];
  const float* b1   = (const float*)d_in[3];
  const float* W2   = (const float*)d_in[4];
  const float* b2   = (const float*)d_in[5];
  const float* labs = (const float*)d_in[6];
  float* scores = (float*)d_out;
  char* ws = (char*)d_ws;

  // Layout (MB): Abf [0,8)  W1t [8,16)  W2t [16,18)  H [18,20)
  //              P [24,40) = 8 x 2 MB bf16    SP [40,48)
  unsigned short* Abf = (unsigned short*)(ws);
  unsigned short* W1t = (unsigned short*)(ws + (8ull << 20));
  unsigned short* W2t = (unsigned short*)(ws + (16ull << 20));
  unsigned short* H   = (unsigned short*)(ws + (18ull << 20));
  unsigned short* P   = (unsigned short*)(ws + (24ull << 20));
  float* SP = (float*)(ws + (40ull << 20));

  dim3 blk(256);
  prep<<<dim3(2048 + 1280), blk, 0, stream>>>(sbj, obj, W1, W2, Abf, W1t, W2t);

  // GEMM1: K=4096, 128^2 tiles, split-K=8 (KSLICE=512), z = XCD, bf16 partials
  mfma_gemm<512><<<dim3(512), blk, 0, stream>>>(Abf, W1t, P, K1);
  combine1<<<dim3(Bn), blk, 0, stream>>>(P, b1, H);
  // GEMM2 fused with score partials (E never materialized)
  gemm2_score<<<dim3(256), blk, 0, stream>>>(H, W2t, b2, labs, SP);
  // final reduce
  score_reduce<<<dim3(128), blk, 0, stream>>>(SP, scores);
}